// Round 13
// baseline (188.618 us; speedup 1.0000x reference)
//
#include <hip/hip_runtime.h>

typedef _Float16 f16;
typedef __attribute__((ext_vector_type(8))) _Float16 f16x8;
typedef __attribute__((ext_vector_type(16))) float f32x16;
typedef __attribute__((ext_vector_type(4))) unsigned u32x4;

#define MM 2048
#define DD 256
#define LOG2E 1.44269504088896340736f

__device__ __forceinline__ void gload_lds16(const void* g, void* l) {
    __builtin_amdgcn_global_load_lds(
        (const __attribute__((address_space(1))) unsigned int*)g,
        (__attribute__((address_space(3))) unsigned int*)l, 16, 0, 0);
}
__device__ __forceinline__ f32x16 mfma32(f16x8 a, f16x8 b, f32x16 c) {
    return __builtin_amdgcn_mfma_f32_32x32x16_f16(a, b, c, 0, 0, 0);
}
__device__ __forceinline__ void plswap(unsigned& a, unsigned& b) {
    asm volatile("v_permlane32_swap_b32 %0, %1" : "+v"(a), "+v"(b));
}
__device__ __forceinline__ unsigned pk2(float a, float b) {
    return __builtin_bit_cast(unsigned, __builtin_amdgcn_cvt_pkrtz(a, b));
}

// Prep (verified R2..R12): memory f32 [2048][256] -> two fp16 copies, 16B-unit layouts.
// Kprep: per 32-row tile b: unit(d8,k) = memory[32b+k][8*d8..8*d8+7]
// VTprep: per 32-row tile b: unit(kg,d) = memory[32b+8kg+e][d], e=0..7
__global__ void prep_kernel(const float* __restrict__ mem,
                            f16* __restrict__ kprep, f16* __restrict__ vtprep) {
    int t = blockIdx.x * blockDim.x + threadIdx.x;
    if (t < 65536) {
        int b = t >> 10, r = t & 1023, u = r >> 5, kk = r & 31;
        const float* src = mem + (b * 32 + kk) * DD + u * 8;
        f16 o8[8];
#pragma unroll
        for (int e = 0; e < 8; ++e) o8[e] = (f16)src[e];
        *(f16x8*)(kprep + (size_t)t * 8) = *(f16x8*)o8;
    } else {
        int t2 = t - 65536;
        int b = t2 >> 10, r = t2 & 1023, u = r >> 8, d = r & 255;
        f16 o8[8];
#pragma unroll
        for (int e = 0; e < 8; ++e) o8[e] = (f16)mem[(b * 32 + u * 8 + e) * DD + d];
        *(f16x8*)(vtprep + (size_t)t2 * 8) = *(f16x8*)o8;
    }
}

// 512 blocks x 256 threads (4 waves x 32 q-rows), R10 body.
// KEY CHANGE vs R10/R12: V-frags are read DIRECTLY FROM GLOBAL (vtprep is 1MB,
// L2-resident, immutable -> no barrier/staging constraint; compiler hoists the
// loads across the QK chain with counted vmcnt). LDS holds only the K double
// buffer (32KB/block); LDS pipe load halves; V stream rides the idle VMEM pipe.
__launch_bounds__(256, 2)
__global__ void attn_kernel(const float* __restrict__ q,
                            const f16* __restrict__ kprep,
                            const f16* __restrict__ vtprep,
                            float* __restrict__ out) {
    __shared__ __align__(16) f16 klds[2][8192];

    const int tid = threadIdx.x;
    const int w = __builtin_amdgcn_readfirstlane(tid >> 6);
    const int lane = tid & 63;
    const int h = lane >> 5;
    const int l31 = lane & 31;
    const int q0 = blockIdx.x * 128 + w * 32;

    // Q B-frags: qf[s] lane(h,l31) elem j = Q[q0+l31][16s+8h+j]  (col=q=l31)
    f16x8 qf[16];
#pragma unroll
    for (int s = 0; s < 16; ++s) {
        const float* src = q + (size_t)(q0 + l31) * DD + s * 16 + h * 8;
        float4 a = *(const float4*)src;
        float4 b2 = *(const float4*)(src + 4);
        f16 t8[8] = {(f16)a.x, (f16)a.y, (f16)a.z, (f16)a.w,
                     (f16)b2.x, (f16)b2.y, (f16)b2.z, (f16)b2.w};
        qf[s] = *(f16x8*)t8;
    }

    f32x16 o[8];
#pragma unroll
    for (int dt = 0; dt < 8; ++dt) o[dt] = (f32x16)(0.f);
    float lpart = 0.f, mrun = -1e30f;
    f16x8 pa0 = (f16x8)(f16)0.f, pa1 = (f16x8)(f16)0.f;  // P frags of tile b-1

    // Per-lane V base offsets (16B units): v0 row (0+h), v1 row (2+h)
    const f16* vbase0 = vtprep + ((0 + h) * 256 + l31) * 8;
    const f16* vbase1 = vtprep + ((2 + h) * 256 + l31) * 8;

#define STAGE_K(b_, c_)                                                   \
    do {                                                                  \
        const f16* s_ = kprep + (size_t)(b_)*8192;                        \
        _Pragma("unroll")                                                 \
        for (int i_ = 0; i_ < 4; ++i_)                                    \
            gload_lds16(s_ + i_ * 2048 + w * 512 + lane * 8,              \
                        &klds[c_][i_ * 2048 + w * 512]);                  \
    } while (0)

    STAGE_K(0, 0);

    for (int b = 0; b < 64; ++b) {
        const int c = b & 1;
        // Barrier: K(b) staged+drained; klds[c^1]'s readers (QK(b-1)) done.
        __syncthreads();
        if (b < 63) STAGE_K(b + 1, c ^ 1);

        // ---- S^T = K Q^T (C-layout: col=q=l31, row=k=(r&3)+8(r>>2)+4h)
        f32x16 s = (f32x16)(0.f);
        __builtin_amdgcn_s_setprio(1);
#pragma unroll
        for (int st = 0; st < 16; ++st) {
            f16x8 ak = *(const f16x8*)(&klds[c][((2 * st + h) * 32 + l31) * 8]);
            s = mfma32(ak, qf[st], s);
        }
        // ---- deferred O += P(b-1) V(b-1): V straight from L2 (no ordering
        // constraint -> loads hoist across the QK chain, vmcnt-counted).
        if (b) {
            const f16* v0p = vbase0 + (size_t)(b - 1) * 8192;
            const f16* v1p = vbase1 + (size_t)(b - 1) * 8192;
#pragma unroll
            for (int dt = 0; dt < 8; ++dt) {
                f16x8 v0 = *(const f16x8*)(v0p + dt * 256);
                f16x8 v1 = *(const f16x8*)(v1p + dt * 256);
                o[dt] = mfma32(pa0, v0, o[dt]);
                o[dt] = mfma32(pa1, v1, o[dt]);
            }
        }
        __builtin_amdgcn_s_setprio(0);

        // ---- softmax (base-2), defer-max
        float sm = s[0];
#pragma unroll
        for (int r = 1; r < 16; ++r) sm = fmaxf(sm, s[r]);
        sm *= LOG2E;
        if (__any(sm > mrun + 8.0f)) {
            sm = fmaxf(sm, __shfl_xor(sm, 32));
            const float mnew = fmaxf(mrun, sm);
            const float fct = __builtin_amdgcn_exp2f(mrun - mnew);
            mrun = mnew;
            lpart *= fct;
            float fr[16];
#pragma unroll
            for (int r = 0; r < 16; ++r)
                fr[r] = __shfl(fct, (r & 3) + 8 * (r >> 2) + 4 * h, 32);
#pragma unroll
            for (int dt = 0; dt < 8; ++dt)
#pragma unroll
                for (int r = 0; r < 16; ++r) o[dt][r] *= fr[r];
        }
        float p[16];
        float rs = 0.f;
#pragma unroll
        for (int r = 0; r < 16; ++r) {
            p[r] = __builtin_amdgcn_exp2f(__builtin_fmaf(s[r], LOG2E, -mrun));
            rs += p[r];
        }
        lpart += rs;

        // ---- pack P(b) -> pa0/pa1 (consumed next iter / epilogue)
        unsigned c0 = pk2(p[0], p[1]),  c1 = pk2(p[2], p[3]);
        unsigned c2 = pk2(p[4], p[5]),  c3 = pk2(p[6], p[7]);
        unsigned c4 = pk2(p[8], p[9]),  c5 = pk2(p[10], p[11]);
        unsigned c6 = pk2(p[12], p[13]), c7 = pk2(p[14], p[15]);
        plswap(c0, c2); plswap(c1, c3);
        plswap(c4, c6); plswap(c5, c7);
        u32x4 pk0 = {c0, c1, c2, c3};
        u32x4 pk1 = {c4, c5, c6, c7};
        pa0 = __builtin_bit_cast(f16x8, pk0);
        pa1 = __builtin_bit_cast(f16x8, pk1);
    }

    // ---- epilogue: PV(63) from global, then store (no barrier needed).
    {
        const f16* v0p = vbase0 + (size_t)63 * 8192;
        const f16* v1p = vbase1 + (size_t)63 * 8192;
#pragma unroll
        for (int dt = 0; dt < 8; ++dt) {
            f16x8 v0 = *(const f16x8*)(v0p + dt * 256);
            f16x8 v1 = *(const f16x8*)(v1p + dt * 256);
            o[dt] = mfma32(pa0, v0, o[dt]);
            o[dt] = mfma32(pa1, v1, o[dt]);
        }
    }

    const float ltot = lpart + __shfl_xor(lpart, 32);
    const float inv = 1.0f / ltot;
    float invr[16];
#pragma unroll
    for (int r = 0; r < 16; ++r)
        invr[r] = __shfl(inv, (r & 3) + 8 * (r >> 2) + 4 * h, 32);
#pragma unroll
    for (int dt = 0; dt < 8; ++dt)
#pragma unroll
        for (int r = 0; r < 16; ++r) {
            const int qrow = (r & 3) + 8 * (r >> 2) + 4 * h;
            out[(size_t)(q0 + qrow) * DD + dt * 32 + l31] = o[dt][r] * invr[r];
        }
}

extern "C" void kernel_launch(void* const* d_in, const int* in_sizes, int n_in,
                              void* d_out, int out_size, void* d_ws, size_t ws_size,
                              hipStream_t stream) {
    const float* memory = (const float*)d_in[0];
    const float* query = (const float*)d_in[1];
    float* out = (float*)d_out;
    f16* kprep = (f16*)d_ws;                 // 1 MB
    f16* vtprep = kprep + (size_t)MM * DD;   // 1 MB
    prep_kernel<<<512, 256, 0, stream>>>(memory, kprep, vtprep);
    attn_kernel<<<512, 256, 0, stream>>>(query, kprep, vtprep, out);
}

// Round 14
// 157.912 us; speedup vs baseline: 1.1944x; 1.1944x over previous
//
#include <hip/hip_runtime.h>

typedef _Float16 f16;
typedef __attribute__((ext_vector_type(8))) _Float16 f16x8;
typedef __attribute__((ext_vector_type(16))) float f32x16;
typedef __attribute__((ext_vector_type(4))) unsigned u32x4;

#define MM 2048
#define DD 256
#define LOG2E 1.44269504088896340736f

__device__ __forceinline__ void gload_lds16(const void* g, void* l) {
    __builtin_amdgcn_global_load_lds(
        (const __attribute__((address_space(1))) unsigned int*)g,
        (__attribute__((address_space(3))) unsigned int*)l, 16, 0, 0);
}
__device__ __forceinline__ f32x16 mfma32(f16x8 a, f16x8 b, f32x16 c) {
    return __builtin_amdgcn_mfma_f32_32x32x16_f16(a, b, c, 0, 0, 0);
}
__device__ __forceinline__ void plswap(unsigned& a, unsigned& b) {
    asm volatile("v_permlane32_swap_b32 %0, %1" : "+v"(a), "+v"(b));
}
__device__ __forceinline__ unsigned pk2(float a, float b) {
    return __builtin_bit_cast(unsigned, __builtin_amdgcn_cvt_pkrtz(a, b));
}

// Prep (verified R2..R13): memory f32 [2048][256] -> two fp16 copies, 16B-unit layouts.
__global__ void prep_kernel(const float* __restrict__ mem,
                            f16* __restrict__ kprep, f16* __restrict__ vtprep) {
    int t = blockIdx.x * blockDim.x + threadIdx.x;
    if (t < 65536) {
        int b = t >> 10, r = t & 1023, u = r >> 5, kk = r & 31;
        const float* src = mem + (b * 32 + kk) * DD + u * 8;
        f16 o8[8];
#pragma unroll
        for (int e = 0; e < 8; ++e) o8[e] = (f16)src[e];
        *(f16x8*)(kprep + (size_t)t * 8) = *(f16x8*)o8;
    } else {
        int t2 = t - 65536;
        int b = t2 >> 10, r = t2 & 1023, u = r >> 8, d = r & 255;
        f16 o8[8];
#pragma unroll
        for (int e = 0; e < 8; ++e) o8[e] = (f16)mem[(b * 32 + u * 8 + e) * DD + d];
        *(f16x8*)(vtprep + (size_t)t2 * 8) = *(f16x8*)o8;
    }
}

// 512 blocks x 256 threads (4 waves x 32 q-rows), R10 geometry + LDS-staged V.
// KEY CHANGE vs R10: hot loop = 8 groups of {read V(g+1) -> QK(2g) -> PV0(g)
// -> QK(2g+1) -> PV1(g)}: 1:1 QK/PV MFMA alternation (dep distance 2 instr)
// with V reads batched ONE GROUP AHEAD (~128cyc >= LDS latency), so no
// lgkmcnt wait lands between MFMAs (R11's failure mode fixed).
__launch_bounds__(256, 2)
__global__ void attn_kernel(const float* __restrict__ q,
                            const f16* __restrict__ kprep,
                            const f16* __restrict__ vtprep,
                            float* __restrict__ out) {
    __shared__ __align__(16) f16 klds[2][8192];
    __shared__ __align__(16) f16 vtlds[2][8192];

    const int tid = threadIdx.x;
    const int w = __builtin_amdgcn_readfirstlane(tid >> 6);
    const int lane = tid & 63;
    const int h = lane >> 5;
    const int l31 = lane & 31;
    const int q0 = blockIdx.x * 128 + w * 32;

    // Q B-frags: qf[s] lane(h,l31) elem j = Q[q0+l31][16s+8h+j]  (col=q=l31)
    f16x8 qf[16];
#pragma unroll
    for (int s = 0; s < 16; ++s) {
        const float* src = q + (size_t)(q0 + l31) * DD + s * 16 + h * 8;
        float4 a = *(const float4*)src;
        float4 b2 = *(const float4*)(src + 4);
        f16 t8[8] = {(f16)a.x, (f16)a.y, (f16)a.z, (f16)a.w,
                     (f16)b2.x, (f16)b2.y, (f16)b2.z, (f16)b2.w};
        qf[s] = *(f16x8*)t8;
    }

    f32x16 o[8];
#pragma unroll
    for (int dt = 0; dt < 8; ++dt) o[dt] = (f32x16)(0.f);
    float lpart = 0.f, mrun = -1e30f;
    f16x8 pa0 = (f16x8)(f16)0.f, pa1 = (f16x8)(f16)0.f;  // P frags of tile b-1

#define STAGE_K(b_, c_)                                                   \
    do {                                                                  \
        const f16* s_ = kprep + (size_t)(b_)*8192;                        \
        _Pragma("unroll")                                                 \
        for (int i_ = 0; i_ < 4; ++i_)                                    \
            gload_lds16(s_ + i_ * 2048 + w * 512 + lane * 8,              \
                        &klds[c_][i_ * 2048 + w * 512]);                  \
    } while (0)
#define STAGE_VT(b_, c_)                                                  \
    do {                                                                  \
        const f16* s_ = vtprep + (size_t)(b_)*8192;                       \
        _Pragma("unroll")                                                 \
        for (int i_ = 0; i_ < 4; ++i_)                                    \
            gload_lds16(s_ + i_ * 2048 + w * 512 + lane * 8,              \
                        &vtlds[c_][i_ * 2048 + w * 512]);                 \
    } while (0)

// softmax (base-2, defer-max) + in-register P pack (R8-verified formulas)
#define SOFTMAX_PACK(s_)                                                       \
    do {                                                                       \
        float sm_ = s_[0];                                                     \
        _Pragma("unroll") for (int r_ = 1; r_ < 16; ++r_)                      \
            sm_ = fmaxf(sm_, s_[r_]);                                          \
        sm_ *= LOG2E;                                                          \
        if (__any(sm_ > mrun + 8.0f)) {                                        \
            sm_ = fmaxf(sm_, __shfl_xor(sm_, 32));                             \
            const float mn_ = fmaxf(mrun, sm_);                                \
            const float fct_ = __builtin_amdgcn_exp2f(mrun - mn_);             \
            mrun = mn_;                                                        \
            lpart *= fct_;                                                     \
            float fr_[16];                                                     \
            _Pragma("unroll") for (int r_ = 0; r_ < 16; ++r_)                  \
                fr_[r_] = __shfl(fct_, (r_ & 3) + 8 * (r_ >> 2) + 4 * h, 32);  \
            _Pragma("unroll") for (int dt_ = 0; dt_ < 8; ++dt_)                \
                _Pragma("unroll") for (int r_ = 0; r_ < 16; ++r_)              \
                    o[dt_][r_] *= fr_[r_];                                     \
        }                                                                      \
        float p_[16], rs_ = 0.f;                                               \
        _Pragma("unroll") for (int r_ = 0; r_ < 16; ++r_) {                    \
            p_[r_] = __builtin_amdgcn_exp2f(                                   \
                __builtin_fmaf(s_[r_], LOG2E, -mrun));                         \
            rs_ += p_[r_];                                                     \
        }                                                                      \
        lpart += rs_;                                                          \
        unsigned c0_ = pk2(p_[0], p_[1]), c1_ = pk2(p_[2], p_[3]);             \
        unsigned c2_ = pk2(p_[4], p_[5]), c3_ = pk2(p_[6], p_[7]);             \
        unsigned c4_ = pk2(p_[8], p_[9]), c5_ = pk2(p_[10], p_[11]);           \
        unsigned c6_ = pk2(p_[12], p_[13]), c7_ = pk2(p_[14], p_[15]);         \
        plswap(c0_, c2_); plswap(c1_, c3_);                                    \
        plswap(c4_, c6_); plswap(c5_, c7_);                                    \
        u32x4 k0_ = {c0_, c1_, c2_, c3_}, k1_ = {c4_, c5_, c6_, c7_};          \
        pa0 = __builtin_bit_cast(f16x8, k0_);                                  \
        pa1 = __builtin_bit_cast(f16x8, k1_);                                  \
    } while (0)

#define RD_K(st_) (*(const f16x8*)(&klds[c][((2 * (st_) + h) * 32 + l31) * 8]))
#define RD_V0(g_) (*(const f16x8*)(&vtlds[c ^ 1][((0 + h) * 256 + (g_)*32 + l31) * 8]))
#define RD_V1(g_) (*(const f16x8*)(&vtlds[c ^ 1][((2 + h) * 256 + (g_)*32 + l31) * 8]))

    STAGE_K(0, 0);

    // ---- peeled iter 0: QK only
    {
        const int c = 0;
        __syncthreads();
        STAGE_K(1, 1);
        STAGE_VT(0, 0);
        f32x16 s = (f32x16)(0.f);
        __builtin_amdgcn_s_setprio(1);
#pragma unroll
        for (int st = 0; st < 16; ++st) s = mfma32(RD_K(st), qf[st], s);
        __builtin_amdgcn_s_setprio(0);
        SOFTMAX_PACK(s);
    }

    // ---- main loop b=1..63: 8 groups of {rd V(g+1), QK, PV0, QK, PV1}
    for (int b = 1; b < 64; ++b) {
        const int c = b & 1;
        __syncthreads();  // K(b)/VT(b-1) resident; klds[c]/vtlds[c] free
        if (b < 63) STAGE_K(b + 1, c ^ 1);
        STAGE_VT(b, c);

        f32x16 s = (f32x16)(0.f);
        __builtin_amdgcn_s_setprio(1);
        f16x8 v0c = RD_V0(0), v1c = RD_V1(0);
#pragma unroll
        for (int g = 0; g < 8; ++g) {
            f16x8 v0n, v1n;
            if (g < 7) { v0n = RD_V0(g + 1); v1n = RD_V1(g + 1); }
            s = mfma32(RD_K(2 * g), qf[2 * g], s);
            o[g] = mfma32(pa0, v0c, o[g]);
            s = mfma32(RD_K(2 * g + 1), qf[2 * g + 1], s);
            o[g] = mfma32(pa1, v1c, o[g]);
            if (g < 7) { v0c = v0n; v1c = v1n; }
        }
        __builtin_amdgcn_s_setprio(0);
        SOFTMAX_PACK(s);
    }

    // ---- epilogue: PV(63) (VT(63) in vtlds[1], staged at iter 63)
    __syncthreads();
    __builtin_amdgcn_s_setprio(1);
    {
        const int c = 0;  // vtlds[c^1] = vtlds[1]
#pragma unroll
        for (int g = 0; g < 8; ++g) {
            o[g] = mfma32(pa0, RD_V0(g), o[g]);
            o[g] = mfma32(pa1, RD_V1(g), o[g]);
        }
    }
    __builtin_amdgcn_s_setprio(0);

    const float ltot = lpart + __shfl_xor(lpart, 32);
    const float inv = 1.0f / ltot;
    float invr[16];
#pragma unroll
    for (int r = 0; r < 16; ++r)
        invr[r] = __shfl(inv, (r & 3) + 8 * (r >> 2) + 4 * h, 32);
#pragma unroll
    for (int dt = 0; dt < 8; ++dt)
#pragma unroll
        for (int r = 0; r < 16; ++r) {
            const int qrow = (r & 3) + 8 * (r >> 2) + 4 * h;
            out[(size_t)(q0 + qrow) * DD + dt * 32 + l31] = o[dt][r] * invr[r];
        }
}

extern "C" void kernel_launch(void* const* d_in, const int* in_sizes, int n_in,
                              void* d_out, int out_size, void* d_ws, size_t ws_size,
                              hipStream_t stream) {
    const float* memory = (const float*)d_in[0];
    const float* query = (const float*)d_in[1];
    float* out = (float*)d_out;
    f16* kprep = (f16*)d_ws;                 // 1 MB
    f16* vtprep = kprep + (size_t)MM * DD;   // 1 MB
    prep_kernel<<<512, 256, 0, stream>>>(memory, kprep, vtprep);
    attn_kernel<<<512, 256, 0, stream>>>(query, kprep, vtprep, out);
}

// Round 15
// 152.200 us; speedup vs baseline: 1.2393x; 1.0375x over previous
//
#include <hip/hip_runtime.h>

typedef _Float16 f16;
typedef __attribute__((ext_vector_type(8))) _Float16 f16x8;
typedef __attribute__((ext_vector_type(16))) float f32x16;
typedef __attribute__((ext_vector_type(4))) unsigned u32x4;

#define MM 2048
#define DD 256
#define LOG2E 1.44269504088896340736f

__device__ __forceinline__ void gload_lds16(const void* g, void* l) {
    __builtin_amdgcn_global_load_lds(
        (const __attribute__((address_space(1))) unsigned int*)g,
        (__attribute__((address_space(3))) unsigned int*)l, 16, 0, 0);
}
__device__ __forceinline__ f32x16 mfma32(f16x8 a, f16x8 b, f32x16 c) {
    return __builtin_amdgcn_mfma_f32_32x32x16_f16(a, b, c, 0, 0, 0);
}
__device__ __forceinline__ void plswap(unsigned& a, unsigned& b) {
    asm volatile("v_permlane32_swap_b32 %0, %1" : "+v"(a), "+v"(b));
}
__device__ __forceinline__ unsigned pk2(float a, float b) {
    return __builtin_bit_cast(unsigned, __builtin_amdgcn_cvt_pkrtz(a, b));
}

// Prep (verified R2..R14): memory f32 [2048][256] -> two fp16 copies, 16B-unit layouts.
__global__ void prep_kernel(const float* __restrict__ mem,
                            f16* __restrict__ kprep, f16* __restrict__ vtprep) {
    int t = blockIdx.x * blockDim.x + threadIdx.x;
    if (t < 65536) {
        int b = t >> 10, r = t & 1023, u = r >> 5, kk = r & 31;
        const float* src = mem + (b * 32 + kk) * DD + u * 8;
        f16 o8[8];
#pragma unroll
        for (int e = 0; e < 8; ++e) o8[e] = (f16)src[e];
        *(f16x8*)(kprep + (size_t)t * 8) = *(f16x8*)o8;
    } else {
        int t2 = t - 65536;
        int b = t2 >> 10, r = t2 & 1023, u = r >> 8, d = r & 255;
        f16 o8[8];
#pragma unroll
        for (int e = 0; e < 8; ++e) o8[e] = (f16)mem[(b * 32 + u * 8 + e) * DD + d];
        *(f16x8*)(vtprep + (size_t)t2 * 8) = *(f16x8*)o8;
    }
}

// 256 blocks x 512 threads (8 waves x 32 q-rows = 256 q/block, 1 block/CU).
// Identical per-wave body to R10 (best: 167us). KEY CHANGE: the two co-resident
// 256-thread blocks are merged, so each K/VT tile is staged ONCE per CU-iter
// (32KB) instead of twice (64KB) -- halves the L2->LDS DMA the per-iter
// __syncthreads() vmcnt(0) drain must wait on.
__launch_bounds__(512, 2)
__global__ void attn_kernel(const float* __restrict__ q,
                            const f16* __restrict__ kprep,
                            const f16* __restrict__ vtprep,
                            float* __restrict__ out) {
    __shared__ __align__(16) f16 klds[2][8192];
    __shared__ __align__(16) f16 vtlds[2][8192];

    const int tid = threadIdx.x;
    const int w = __builtin_amdgcn_readfirstlane(tid >> 6);  // 0..7
    const int lane = tid & 63;
    const int h = lane >> 5;
    const int l31 = lane & 31;
    const int q0 = blockIdx.x * 256 + w * 32;

    // Q B-frags: qf[s] lane(h,l31) elem j = Q[q0+l31][16s+8h+j]  (col=q=l31)
    f16x8 qf[16];
#pragma unroll
    for (int s = 0; s < 16; ++s) {
        const float* src = q + (size_t)(q0 + l31) * DD + s * 16 + h * 8;
        float4 a = *(const float4*)src;
        float4 b2 = *(const float4*)(src + 4);
        f16 t8[8] = {(f16)a.x, (f16)a.y, (f16)a.z, (f16)a.w,
                     (f16)b2.x, (f16)b2.y, (f16)b2.z, (f16)b2.w};
        qf[s] = *(f16x8*)t8;
    }

    f32x16 o[8];
#pragma unroll
    for (int dt = 0; dt < 8; ++dt) o[dt] = (f32x16)(0.f);
    float lpart = 0.f, mrun = -1e30f;
    f16x8 pa0 = (f16x8)(f16)0.f, pa1 = (f16x8)(f16)0.f;  // P frags of tile b-1

    // 512 threads stage a 16KB tile in 2 gload_lds rounds (1KB contiguous
    // chunk per wave per round: dest = wave-uniform base + lane*16).
#define STAGE_K(b_, c_)                                                   \
    do {                                                                  \
        const f16* s_ = kprep + (size_t)(b_)*8192;                        \
        _Pragma("unroll")                                                 \
        for (int i_ = 0; i_ < 2; ++i_)                                    \
            gload_lds16(s_ + i_ * 4096 + w * 512 + lane * 8,              \
                        &klds[c_][i_ * 4096 + w * 512]);                  \
    } while (0)
#define STAGE_VT(b_, c_)                                                  \
    do {                                                                  \
        const f16* s_ = vtprep + (size_t)(b_)*8192;                       \
        _Pragma("unroll")                                                 \
        for (int i_ = 0; i_ < 2; ++i_)                                    \
            gload_lds16(s_ + i_ * 4096 + w * 512 + lane * 8,              \
                        &vtlds[c_][i_ * 4096 + w * 512]);                 \
    } while (0)

    STAGE_K(0, 0);

    for (int b = 0; b < 64; ++b) {
        const int c = b & 1;
        // Barrier: K(b) + VT(b-1) staged+drained; klds[c^1]/vtlds[c] free.
        __syncthreads();
        if (b < 63) STAGE_K(b + 1, c ^ 1);
        STAGE_VT(b, c);  // consumed by PV at iter b+1 (barrier-fenced)

        // ---- S^T = K Q^T (C-layout: col=q=l31, row=k=(r&3)+8(r>>2)+4h)
        f32x16 s = (f32x16)(0.f);
        __builtin_amdgcn_s_setprio(1);
#pragma unroll
        for (int st = 0; st < 16; ++st) {
            f16x8 ak = *(const f16x8*)(&klds[c][((2 * st + h) * 32 + l31) * 8]);
            s = mfma32(ak, qf[st], s);
        }
        // ---- deferred O += P(b-1) V(b-1): independent of s; issues while the
        // QK chain drains; softmax below overlaps this MFMA tail.
        if (b) {
#pragma unroll
            for (int dt = 0; dt < 8; ++dt) {
                f16x8 v0 = *(const f16x8*)(&vtlds[c ^ 1][((0 + h) * 256 + dt * 32 + l31) * 8]);
                f16x8 v1 = *(const f16x8*)(&vtlds[c ^ 1][((2 + h) * 256 + dt * 32 + l31) * 8]);
                o[dt] = mfma32(pa0, v0, o[dt]);
                o[dt] = mfma32(pa1, v1, o[dt]);
            }
        }
        __builtin_amdgcn_s_setprio(0);

        // ---- softmax (base-2), defer-max
        float sm = s[0];
#pragma unroll
        for (int r = 1; r < 16; ++r) sm = fmaxf(sm, s[r]);
        sm *= LOG2E;
        if (__any(sm > mrun + 8.0f)) {
            sm = fmaxf(sm, __shfl_xor(sm, 32));
            const float mnew = fmaxf(mrun, sm);
            const float fct = __builtin_amdgcn_exp2f(mrun - mnew);
            mrun = mnew;
            lpart *= fct;
            float fr[16];
#pragma unroll
            for (int r = 0; r < 16; ++r)
                fr[r] = __shfl(fct, (r & 3) + 8 * (r >> 2) + 4 * h, 32);
#pragma unroll
            for (int dt = 0; dt < 8; ++dt)
#pragma unroll
                for (int r = 0; r < 16; ++r) o[dt][r] *= fr[r];
        }
        float p[16];
        float rs = 0.f;
#pragma unroll
        for (int r = 0; r < 16; ++r) {
            p[r] = __builtin_amdgcn_exp2f(__builtin_fmaf(s[r], LOG2E, -mrun));
            rs += p[r];
        }
        lpart += rs;

        // ---- pack P(b) -> pa0/pa1 (consumed next iter / epilogue)
        unsigned c0 = pk2(p[0], p[1]),  c1 = pk2(p[2], p[3]);
        unsigned c2 = pk2(p[4], p[5]),  c3 = pk2(p[6], p[7]);
        unsigned c4 = pk2(p[8], p[9]),  c5 = pk2(p[10], p[11]);
        unsigned c6 = pk2(p[12], p[13]), c7 = pk2(p[14], p[15]);
        plswap(c0, c2); plswap(c1, c3);
        plswap(c4, c6); plswap(c5, c7);
        u32x4 pk0 = {c0, c1, c2, c3};
        u32x4 pk1 = {c4, c5, c6, c7};
        pa0 = __builtin_bit_cast(f16x8, pk0);
        pa1 = __builtin_bit_cast(f16x8, pk1);
    }

    // ---- epilogue: PV(63) (VT(63) in vtlds[1], staged at iter 63), then store.
    __syncthreads();
    __builtin_amdgcn_s_setprio(1);
#pragma unroll
    for (int dt = 0; dt < 8; ++dt) {
        f16x8 v0 = *(const f16x8*)(&vtlds[1][((0 + h) * 256 + dt * 32 + l31) * 8]);
        f16x8 v1 = *(const f16x8*)(&vtlds[1][((2 + h) * 256 + dt * 32 + l31) * 8]);
        o[dt] = mfma32(pa0, v0, o[dt]);
        o[dt] = mfma32(pa1, v1, o[dt]);
    }
    __builtin_amdgcn_s_setprio(0);

    const float ltot = lpart + __shfl_xor(lpart, 32);
    const float inv = 1.0f / ltot;
    float invr[16];
#pragma unroll
    for (int r = 0; r < 16; ++r)
        invr[r] = __shfl(inv, (r & 3) + 8 * (r >> 2) + 4 * h, 32);
#pragma unroll
    for (int dt = 0; dt < 8; ++dt)
#pragma unroll
        for (int r = 0; r < 16; ++r) {
            const int qrow = (r & 3) + 8 * (r >> 2) + 4 * h;
            out[(size_t)(q0 + qrow) * DD + dt * 32 + l31] = o[dt][r] * invr[r];
        }
}

extern "C" void kernel_launch(void* const* d_in, const int* in_sizes, int n_in,
                              void* d_out, int out_size, void* d_ws, size_t ws_size,
                              hipStream_t stream) {
    const float* memory = (const float*)d_in[0];
    const float* query = (const float*)d_in[1];
    float* out = (float*)d_out;
    f16* kprep = (f16*)d_ws;                 // 1 MB
    f16* vtprep = kprep + (size_t)MM * DD;   // 1 MB
    prep_kernel<<<512, 256, 0, stream>>>(memory, kprep, vtprep);
    attn_kernel<<<256, 512, 0, stream>>>(query, kprep, vtprep, out);
}

// Round 16
// 150.881 us; speedup vs baseline: 1.2501x; 1.0087x over previous
//
#include <hip/hip_runtime.h>

typedef _Float16 f16;
typedef __attribute__((ext_vector_type(8))) _Float16 f16x8;
typedef __attribute__((ext_vector_type(16))) float f32x16;
typedef __attribute__((ext_vector_type(4))) unsigned u32x4;

#define MM 2048
#define DD 256
#define LOG2E 1.44269504088896340736f

__device__ __forceinline__ void gload_lds16(const void* g, void* l) {
    __builtin_amdgcn_global_load_lds(
        (const __attribute__((address_space(1))) unsigned int*)g,
        (__attribute__((address_space(3))) unsigned int*)l, 16, 0, 0);
}
__device__ __forceinline__ f32x16 mfma32(f16x8 a, f16x8 b, f32x16 c) {
    return __builtin_amdgcn_mfma_f32_32x32x16_f16(a, b, c, 0, 0, 0);
}
__device__ __forceinline__ void plswap(unsigned& a, unsigned& b) {
    asm volatile("v_permlane32_swap_b32 %0, %1" : "+v"(a), "+v"(b));
}
__device__ __forceinline__ unsigned pk2(float a, float b) {
    return __builtin_bit_cast(unsigned, __builtin_amdgcn_cvt_pkrtz(a, b));
}

// Prep (verified R2..R15): memory f32 [2048][256] -> two fp16 copies, 16B-unit layouts.
__global__ void prep_kernel(const float* __restrict__ mem,
                            f16* __restrict__ kprep, f16* __restrict__ vtprep) {
    int t = blockIdx.x * blockDim.x + threadIdx.x;
    if (t < 65536) {
        int b = t >> 10, r = t & 1023, u = r >> 5, kk = r & 31;
        const float* src = mem + (b * 32 + kk) * DD + u * 8;
        f16 o8[8];
#pragma unroll
        for (int e = 0; e < 8; ++e) o8[e] = (f16)src[e];
        *(f16x8*)(kprep + (size_t)t * 8) = *(f16x8*)o8;
    } else {
        int t2 = t - 65536;
        int b = t2 >> 10, r = t2 & 1023, u = r >> 8, d = r & 255;
        f16 o8[8];
#pragma unroll
        for (int e = 0; e < 8; ++e) o8[e] = (f16)mem[(b * 32 + u * 8 + e) * DD + d];
        *(f16x8*)(vtprep + (size_t)t2 * 8) = *(f16x8*)o8;
    }
}

// 256 blocks x 512 threads (8 waves x 32 q-rows), R15 per-tile body.
// KEY CHANGE vs R15: PAIR-UNROLLED loop -- ONE barrier per 2 KV tiles (64 keys),
// 4-deep K and VT LDS rings (128 KB, 1 block/CU). Staging schedule derived from
// first-read pairs: at pair p stage K(2p+2),K(2p+3),VT(2p+1),VT(2p+2); the VT
// straddle keeps the 4-buffer ring WAR-safe given PV's one-tile lag.
__launch_bounds__(512, 2)
__global__ void attn_kernel(const float* __restrict__ q,
                            const f16* __restrict__ kprep,
                            const f16* __restrict__ vtprep,
                            float* __restrict__ out) {
    __shared__ __align__(16) f16 klds[4][8192];
    __shared__ __align__(16) f16 vtlds[4][8192];

    const int tid = threadIdx.x;
    const int w = __builtin_amdgcn_readfirstlane(tid >> 6);  // 0..7
    const int lane = tid & 63;
    const int h = lane >> 5;
    const int l31 = lane & 31;
    const int q0 = blockIdx.x * 256 + w * 32;

    // Q B-frags: qf[s] lane(h,l31) elem j = Q[q0+l31][16s+8h+j]  (col=q=l31)
    f16x8 qf[16];
#pragma unroll
    for (int s = 0; s < 16; ++s) {
        const float* src = q + (size_t)(q0 + l31) * DD + s * 16 + h * 8;
        float4 a = *(const float4*)src;
        float4 b2 = *(const float4*)(src + 4);
        f16 t8[8] = {(f16)a.x, (f16)a.y, (f16)a.z, (f16)a.w,
                     (f16)b2.x, (f16)b2.y, (f16)b2.z, (f16)b2.w};
        qf[s] = *(f16x8*)t8;
    }

    f32x16 o[8];
#pragma unroll
    for (int dt = 0; dt < 8; ++dt) o[dt] = (f32x16)(0.f);
    float lpart = 0.f, mrun = -1e30f;
    f16x8 pa0 = (f16x8)(f16)0.f, pa1 = (f16x8)(f16)0.f;  // P frags of prev tile

    // 512 threads stage a 16KB tile in 2 gload rounds (wave-linear dest).
#define STAGE_K(t_)                                                       \
    do {                                                                  \
        const f16* s_ = kprep + (size_t)(t_)*8192;                        \
        _Pragma("unroll")                                                 \
        for (int i_ = 0; i_ < 2; ++i_)                                    \
            gload_lds16(s_ + i_ * 4096 + w * 512 + lane * 8,              \
                        &klds[(t_) & 3][i_ * 4096 + w * 512]);            \
    } while (0)
#define STAGE_VT(t_)                                                      \
    do {                                                                  \
        const f16* s_ = vtprep + (size_t)(t_)*8192;                       \
        _Pragma("unroll")                                                 \
        for (int i_ = 0; i_ < 2; ++i_)                                    \
            gload_lds16(s_ + i_ * 4096 + w * 512 + lane * 8,              \
                        &vtlds[(t_) & 3][i_ * 4096 + w * 512]);           \
    } while (0)

// QK: s_ = K(t_) Q^T, 16 chained MFMAs (C: col=q=l31, row=k=(r&3)+8(r>>2)+4h)
#define QK(t_, s_)                                                            \
    do {                                                                      \
        const f16* kb_ = &klds[(t_) & 3][0];                                  \
        _Pragma("unroll")                                                     \
        for (int st_ = 0; st_ < 16; ++st_) {                                  \
            f16x8 ak_ = *(const f16x8*)(kb_ + ((2 * st_ + h) * 32 + l31) * 8);\
            s_ = mfma32(ak_, qf[st_], s_);                                    \
        }                                                                     \
    } while (0)

// PV: o += P(prev) V(t_), pa0/pa1 in regs, V from vtlds ring
#define PV(t_)                                                                 \
    do {                                                                       \
        const f16* vb_ = &vtlds[(t_) & 3][0];                                  \
        _Pragma("unroll")                                                      \
        for (int dt_ = 0; dt_ < 8; ++dt_) {                                    \
            f16x8 v0_ = *(const f16x8*)(vb_ + ((0 + h) * 256 + dt_ * 32 + l31) * 8); \
            f16x8 v1_ = *(const f16x8*)(vb_ + ((2 + h) * 256 + dt_ * 32 + l31) * 8); \
            o[dt_] = mfma32(pa0, v0_, o[dt_]);                                 \
            o[dt_] = mfma32(pa1, v1_, o[dt_]);                                 \
        }                                                                      \
    } while (0)

// softmax (base-2, defer-max) + in-register P pack -> pa0/pa1
#define SOFTMAX_PACK(s_)                                                       \
    do {                                                                       \
        float sm_ = s_[0];                                                     \
        _Pragma("unroll") for (int r_ = 1; r_ < 16; ++r_)                      \
            sm_ = fmaxf(sm_, s_[r_]);                                          \
        sm_ *= LOG2E;                                                          \
        if (__any(sm_ > mrun + 8.0f)) {                                        \
            sm_ = fmaxf(sm_, __shfl_xor(sm_, 32));                             \
            const float mn_ = fmaxf(mrun, sm_);                                \
            const float fct_ = __builtin_amdgcn_exp2f(mrun - mn_);             \
            mrun = mn_;                                                        \
            lpart *= fct_;                                                     \
            float fr_[16];                                                     \
            _Pragma("unroll") for (int r_ = 0; r_ < 16; ++r_)                  \
                fr_[r_] = __shfl(fct_, (r_ & 3) + 8 * (r_ >> 2) + 4 * h, 32);  \
            _Pragma("unroll") for (int dt_ = 0; dt_ < 8; ++dt_)                \
                _Pragma("unroll") for (int r_ = 0; r_ < 16; ++r_)              \
                    o[dt_][r_] *= fr_[r_];                                     \
        }                                                                      \
        float p_[16], rs_ = 0.f;                                               \
        _Pragma("unroll") for (int r_ = 0; r_ < 16; ++r_) {                    \
            p_[r_] = __builtin_amdgcn_exp2f(                                   \
                __builtin_fmaf(s_[r_], LOG2E, -mrun));                         \
            rs_ += p_[r_];                                                     \
        }                                                                      \
        lpart += rs_;                                                          \
        unsigned c0_ = pk2(p_[0], p_[1]), c1_ = pk2(p_[2], p_[3]);             \
        unsigned c2_ = pk2(p_[4], p_[5]), c3_ = pk2(p_[6], p_[7]);             \
        unsigned c4_ = pk2(p_[8], p_[9]), c5_ = pk2(p_[10], p_[11]);           \
        unsigned c6_ = pk2(p_[12], p_[13]), c7_ = pk2(p_[14], p_[15]);         \
        plswap(c0_, c2_); plswap(c1_, c3_);                                    \
        plswap(c4_, c6_); plswap(c5_, c7_);                                    \
        u32x4 k0_ = {c0_, c1_, c2_, c3_}, k1_ = {c4_, c5_, c6_, c7_};          \
        pa0 = __builtin_bit_cast(f16x8, k0_);                                  \
        pa1 = __builtin_bit_cast(f16x8, k1_);                                  \
    } while (0)

    // Prologue: K(0), K(1), VT(0) (drained by the first in-loop barrier).
    STAGE_K(0);
    STAGE_K(1);
    STAGE_VT(0);

    // Main loop: 32 pairs; ONE barrier per pair.
    for (int p = 0; p < 32; ++p) {
        const int t0 = 2 * p, t1 = 2 * p + 1;
        // Barrier: K(t0),K(t1),VT(t0) [+VT(t1-? staged earlier)] resident;
        // ring buffers being overwritten below had their last read pre-barrier.
        __syncthreads();
        if (p < 31) { STAGE_K(t0 + 2); STAGE_K(t1 + 2); }
        STAGE_VT(t1);                 // first read: PV(t1) next pair
        if (p < 31) STAGE_VT(t1 + 1); // first read: PV(t1+1) next pair

        __builtin_amdgcn_s_setprio(1);
        f32x16 s0 = (f32x16)(0.f);
        QK(t0, s0);
        if (p) PV(t0 - 1);
        __builtin_amdgcn_s_setprio(0);
        SOFTMAX_PACK(s0);

        __builtin_amdgcn_s_setprio(1);
        f32x16 s1 = (f32x16)(0.f);
        QK(t1, s1);
        PV(t0);
        __builtin_amdgcn_s_setprio(0);
        SOFTMAX_PACK(s1);
    }

    // Epilogue: PV(63) (VT(63) staged at pair 31; barrier drains it).
    __syncthreads();
    __builtin_amdgcn_s_setprio(1);
    PV(63);
    __builtin_amdgcn_s_setprio(0);

    const float ltot = lpart + __shfl_xor(lpart, 32);
    const float inv = 1.0f / ltot;
    float invr[16];
#pragma unroll
    for (int r = 0; r < 16; ++r)
        invr[r] = __shfl(inv, (r & 3) + 8 * (r >> 2) + 4 * h, 32);
#pragma unroll
    for (int dt = 0; dt < 8; ++dt)
#pragma unroll
        for (int r = 0; r < 16; ++r) {
            const int qrow = (r & 3) + 8 * (r >> 2) + 4 * h;
            out[(size_t)(q0 + qrow) * DD + dt * 32 + l31] = o[dt][r] * invr[r];
        }
}

extern "C" void kernel_launch(void* const* d_in, const int* in_sizes, int n_in,
                              void* d_out, int out_size, void* d_ws, size_t ws_size,
                              hipStream_t stream) {
    const float* memory = (const float*)d_in[0];
    const float* query = (const float*)d_in[1];
    float* out = (float*)d_out;
    f16* kprep = (f16*)d_ws;                 // 1 MB
    f16* vtprep = kprep + (size_t)MM * DD;   // 1 MB
    prep_kernel<<<512, 256, 0, stream>>>(memory, kprep, vtprep);
    attn_kernel<<<256, 512, 0, stream>>>(query, kprep, vtprep, out);
}